// Round 21
// baseline (553.867 us; speedup 1.0000x reference)
//
#include <hip/hip_runtime.h>
#include <math.h>

#define HIDDEN 4096
#define NH 32
#define HD 128
#define PLEN 10
#define SEQQ 2048
#define QT 32
#define KT 64
#define QKVLD 12288
#define MROWS 2176   // 2048 hidden rows + 128 padded adapter rows

typedef __attribute__((ext_vector_type(8))) _Float16 f16x8;
typedef __attribute__((ext_vector_type(4))) float f32x4;

// async global->LDS, 16 bytes per lane; LDS dest is wave-uniform base + lane*16
#define GLD16(g, l) __builtin_amdgcn_global_load_lds( \
        (const __attribute__((address_space(1))) void*)(g), \
        (__attribute__((address_space(3))) void*)(l), 16, 0, 0)

// ---------------- fp32 -> fp16 plane, 8 elems/thread ----------------
__global__ __launch_bounds__(256) void cvt_f16_kernel(
    const float* __restrict__ x, _Float16* __restrict__ y, int n8)
{
    int idx = blockIdx.x * 256 + threadIdx.x;
    if (idx >= n8) return;
    const float4* xp = (const float4*)x;
    float4 a = xp[idx * 2], b = xp[idx * 2 + 1];
    f16x8 o;
    o[0] = (_Float16)a.x; o[1] = (_Float16)a.y; o[2] = (_Float16)a.z; o[3] = (_Float16)a.w;
    o[4] = (_Float16)b.x; o[5] = (_Float16)b.y; o[6] = (_Float16)b.z; o[7] = (_Float16)b.w;
    *(f16x8*)(y + (size_t)idx * 8) = o;
}

// ---------------- 3 x fp32 weight -> contiguous fp16 (one launch) ----------------
__global__ __launch_bounds__(256) void cvt3_f16_kernel(
    const float* __restrict__ w0, const float* __restrict__ w1, const float* __restrict__ w2,
    _Float16* __restrict__ y)
{
    int idx = blockIdx.x * 256 + threadIdx.x;       // < 3 * 2^21
    int sel = idx >> 21;
    int off = idx & ((1 << 21) - 1);
    const float* src = (sel == 0) ? w0 : (sel == 1) ? w1 : w2;
    const float4* xp = (const float4*)src;
    float4 a = xp[off * 2], b = xp[off * 2 + 1];
    f16x8 o;
    o[0] = (_Float16)a.x; o[1] = (_Float16)a.y; o[2] = (_Float16)a.z; o[3] = (_Float16)a.w;
    o[4] = (_Float16)b.x; o[5] = (_Float16)b.y; o[6] = (_Float16)b.z; o[7] = (_Float16)b.w;
    *(f16x8*)(y + (size_t)idx * 8) = o;
}

// ---------------- adapter (10x4096) -> zero-padded 128x4096 fp16 ----------------
__global__ __launch_bounds__(256) void cvt_pad_f16_kernel(
    const float* __restrict__ src, _Float16* __restrict__ y)
{
    int idx = blockIdx.x * 256 + threadIdx.x;
    int row = idx >> 9;
    f16x8 o;
    if (row < PLEN) {
        const float4* xp = (const float4*)src;
        float4 a = xp[idx * 2], b = xp[idx * 2 + 1];
        o[0] = (_Float16)a.x; o[1] = (_Float16)a.y; o[2] = (_Float16)a.z; o[3] = (_Float16)a.w;
        o[4] = (_Float16)b.x; o[5] = (_Float16)b.y; o[6] = (_Float16)b.z; o[7] = (_Float16)b.w;
    } else {
#pragma unroll
        for (int i = 0; i < 8; ++i) o[i] = (_Float16)0.0f;
    }
    *(f16x8*)(y + (size_t)idx * 8) = o;
}

// ---------------- fp16 MFMA GEMM NT, 128x128, counted-vmcnt double-buffer ----------------
// Block mapping: swizzled ids < gx*16 use the proven gy=16 M-major walk
// (consecutive sw share B panel; L2-resident B set = 32MB). Remaining ids are
// adapter tail blocks at m0 = 2048. Wo launch (gy=16) has no tail.
template <typename OT>
__global__ __launch_bounds__(256) void gemm_f16_kernel(
    const _Float16* __restrict__ A, const _Float16* __restrict__ B,
    OT* __restrict__ C, int N, int K, int Mstore)
{
    __shared__ _Float16 lds[2 * 16384];   // [dbuf][A plane 8192 | B plane 8192]

    const int tid = threadIdx.x;
    const int lane = tid & 63;
    const int wave = tid >> 6;

    // XCD-aware bijective swizzle (nwg % 8 == 0 for our grids)
    const int gx = gridDim.x;
    const int nwg = gx * gridDim.y;
    const int flat = blockIdx.y * gx + blockIdx.x;
    const int cpx = nwg >> 3;
    const int sw = (flat & 7) * cpx + (flat >> 3);

    const int qkvB = gx << 4;            // gx*16 blocks in the main gy=16 walk
    int m0, n0;
    if (sw < qkvB) {                     // main part: gy=16 M-major walk
        m0 = (sw & 15) * 128;
        n0 = (sw >> 4) * 128;
    } else {                             // adapter tail (only when gridDim.y == 17)
        m0 = 2048;
        n0 = (sw - qkvB) * 128;
    }

    const _Float16* srcp = (wave < 2) ? A : B;
    const int tb = ((wave < 2) ? m0 : n0) + (wave & 1) * 64;
    const int swz = ((lane & 7) ^ ((lane >> 3) & 7)) << 3;   // pre-swizzled global col
    const _Float16* p0 = srcp + (size_t)(tb + (lane >> 3)) * K + swz;
    const int ldso = (wave >> 1) * 8192 + (wave & 1) * 4096;

    const int lr = lane & 15;
    const int lq = lane >> 4;
    const int wm = (wave >> 1) * 64;
    const int wn = (wave & 1) * 64;

    f32x4 acc[4][4];
#pragma unroll
    for (int m = 0; m < 4; ++m)
#pragma unroll
        for (int n = 0; n < 4; ++n) acc[m][n] = (f32x4){0.f, 0.f, 0.f, 0.f};

#define STAGE(bufsel, tt) do { \
        _Float16* dst_ = &lds[(bufsel) * 16384 + ldso]; \
        const _Float16* src_ = p0 + ((size_t)(tt) << 6); \
        GLD16(src_ + 0 * 8 * (size_t)K, dst_ + 0 * 512); \
        GLD16(src_ + 1 * 8 * (size_t)K, dst_ + 1 * 512); \
        GLD16(src_ + 2 * 8 * (size_t)K, dst_ + 2 * 512); \
        GLD16(src_ + 3 * 8 * (size_t)K, dst_ + 3 * 512); \
        GLD16(src_ + 4 * 8 * (size_t)K, dst_ + 4 * 512); \
        GLD16(src_ + 5 * 8 * (size_t)K, dst_ + 5 * 512); \
        GLD16(src_ + 6 * 8 * (size_t)K, dst_ + 6 * 512); \
        GLD16(src_ + 7 * 8 * (size_t)K, dst_ + 7 * 512); \
    } while (0)

    const int NK = K >> 6;      // >= 2 for all our shapes (K = 4096)
    STAGE(0, 0);
    STAGE(1, 1);

    for (int t = 0; t < NK; ++t) {
        const int cur = t & 1;
        if (t == NK - 1) asm volatile("s_waitcnt vmcnt(0)" ::: "memory");
        else             asm volatile("s_waitcnt vmcnt(8)" ::: "memory");
        __builtin_amdgcn_s_barrier();     // collective: tile t resident for all waves

        const _Float16* la = &lds[cur * 16384];
        const _Float16* lb = &lds[cur * 16384 + 8192];
#pragma unroll
        for (int kc = 0; kc < 2; ++kc) {
            f16x8 af[4], bf[4];
#pragma unroll
            for (int m = 0; m < 4; ++m) {
                int r = wm + m * 16 + lr;
                af[m] = *(const f16x8*)&la[(r << 6) + ((((kc << 2) + lq) ^ (lr & 7)) << 3)];
            }
#pragma unroll
            for (int n = 0; n < 4; ++n) {
                int r = wn + n * 16 + lr;
                bf[n] = *(const f16x8*)&lb[(r << 6) + ((((kc << 2) + lq) ^ (lr & 7)) << 3)];
            }
            __builtin_amdgcn_s_setprio(1);
#pragma unroll
            for (int m = 0; m < 4; ++m)
#pragma unroll
                for (int n = 0; n < 4; ++n)
                    acc[m][n] = __builtin_amdgcn_mfma_f32_16x16x32_f16(af[m], bf[n], acc[m][n], 0, 0, 0);
            __builtin_amdgcn_s_setprio(0);
        }
        __builtin_amdgcn_s_barrier();     // all waves done reading buf[cur]
        if (t + 2 < NK) STAGE(cur, t + 2);
    }
#undef STAGE

    // C layout: col = lane&15, row = (lane>>4)*4 + j
#pragma unroll
    for (int m = 0; m < 4; ++m) {
        const int row = m0 + wm + m * 16 + lq * 4;
#pragma unroll
        for (int n = 0; n < 4; ++n) {
            const int col = n0 + wn + n * 16 + lr;
#pragma unroll
            for (int j = 0; j < 4; ++j)
                if (row + j < Mstore)
                    C[(size_t)(row + j) * N + col] = (OT)acc[m][n][j];
        }
    }
}

// ---------------- RoPE cos/sin tables ----------------
__global__ void rope_table_kernel(const int* __restrict__ pos,
                                  float* __restrict__ cosT, float* __restrict__ sinT)
{
    int s = blockIdx.x;
    int j = threadIdx.x;               // 0..63
    float p = (float)pos[s];
    float expnt = (2.0f * (float)j) * (1.0f / 128.0f);
    float inv_freq = powf(10000.0f, -expnt);
    float f = p * inv_freq;
    cosT[s * 64 + j] = cosf(f);
    sinT[s * 64 + j] = sinf(f);
}

// ---------------- fused: RoPE (Q,K in place) + V -> Vt transpose ----------------
__global__ __launch_bounds__(256) void rope_vtrans_kernel(
    _Float16* __restrict__ qkv, const float* __restrict__ cosT, const float* __restrict__ sinT,
    _Float16* __restrict__ vt)
{
    __shared__ _Float16 Vsh[64][136];
    const int h = blockIdx.y;
    const int s0 = blockIdx.x * 64;
    const int tid = threadIdx.x;

    // ---- V tile load (for transpose) ----
#pragma unroll
    for (int i = 0; i < 4; ++i) {
        int flat = tid + 256 * i;          // 0..1023
        int r = flat >> 4;
        int c8 = (flat & 15) * 8;
        *(f16x8*)&Vsh[r][c8] =
            *(const f16x8*)(qkv + (size_t)(s0 + r) * QKVLD + 2 * HIDDEN + h * HD + c8);
    }

    // ---- RoPE on Q and K rows of this (s-tile, head) ----
#pragma unroll
    for (int i = 0; i < 16; ++i) {
        int flat = tid + 256 * i;          // 0..4095
        int r = flat >> 6;                 // 0..63
        int d = flat & 63;
        int s = s0 + r;
        float c = cosT[s * 64 + d], sn = sinT[s * 64 + d];
        size_t base = (size_t)s * QKVLD + h * HD + d;
        float a = (float)qkv[base], b = (float)qkv[base + 64];
        qkv[base]      = (_Float16)(a * c - b * sn);
        qkv[base + 64] = (_Float16)(b * c + a * sn);
        size_t kb = base + HIDDEN;
        a = (float)qkv[kb]; b = (float)qkv[kb + 64];
        qkv[kb]      = (_Float16)(a * c - b * sn);
        qkv[kb + 64] = (_Float16)(b * c + a * sn);
    }

    __syncthreads();
    // ---- Vt store ----
#pragma unroll
    for (int pass = 0; pass < 4; ++pass) {
        int d = pass * 32 + (tid >> 3);
        int sb = (tid & 7) * 8;
        f16x8 o;
#pragma unroll
        for (int e = 0; e < 8; ++e) o[e] = Vsh[sb + e][d];
        *(f16x8*)(vt + ((size_t)h * HD + d) * SEQQ + s0 + sb) = o;
    }
}

// ---------------- MFMA fp16 flash attention, causal + gated prefix (R19 structure) ----------------
// grid (NH, 32): qt = 31 - blockIdx.y (longest-first). 2 barriers/tile.
__global__ __launch_bounds__(256) void attn_f16_kernel(
    const _Float16* __restrict__ Qf, const _Float16* __restrict__ Kf,
    const _Float16* __restrict__ Vtf,
    const _Float16* __restrict__ kp, const _Float16* __restrict__ vp,
    const float* __restrict__ gate, _Float16* __restrict__ out)
{
    __shared__ _Float16 Ks[64 * 128];    // 16KB K tile [j][128]
    __shared__ _Float16 Vs[128 * 64];    // 16KB Vt tile [d][64]
    __shared__ _Float16 Psh[4][16][72];  // P tile (f16) per wave (wave-private)
    __shared__ float Pp[4][16][12];      // gated prefix probs per wave

    const int h = blockIdx.x;
    const int qt = (gridDim.y - 1) - blockIdx.y;   // longest-first
    const int q0 = qt * 64;
    const int tid = threadIdx.x;
    const int wave = tid >> 6;
    const int lane = tid & 63;
    const int lr = lane & 15;
    const int lq = lane >> 4;
    const float scale = 0.088388347648318447f;                 // 1/sqrt(128)
    const float scale2 = 0.088388347648318447f * 1.4426950408889634f;  // *log2(e)

    const int qrow = q0 + wave * 16 + lr;
    f16x8 qh[4];
#pragma unroll
    for (int c = 0; c < 4; ++c)
        qh[c] = *(const f16x8*)(Qf + (size_t)qrow * QKVLD + h * HD + c * 32 + lq * 8);

    f32x4 accO[8];
#pragma unroll
    for (int n = 0; n < 8; ++n) accO[n] = (f32x4){0.f, 0.f, 0.f, 0.f};
    float m_run[4] = {-INFINITY, -INFINITY, -INFINITY, -INFINITY};
    float l_run[4] = {0.f, 0.f, 0.f, 0.f};

    const int ntiles = qt + 1;
    for (int t = 0; t < ntiles; ++t) {
        const int j0 = t * 64;
        __syncthreads();                 // prev tile's K/V reads done

        // ---- stage K tile (wave w -> rows 16w..16w+15) ----
        {
            const int rl = lane >> 4;
            const int ch = lane & 15;
#pragma unroll
            for (int ii = 0; ii < 4; ++ii) {
                int r = wave * 16 + ii * 4 + rl;
                int chs = ch ^ (r & 7);
                const _Float16* g = Kf + (size_t)(j0 + r) * QKVLD + h * HD + chs * 8;
                GLD16(g, &Ks[(wave * 16 + ii * 4) * 128]);
            }
        }
        // ---- stage Vt tile (wave w -> d rows 32w..32w+31) ----
        {
            const int dl = lane >> 3;
            const int vch = lane & 7;
#pragma unroll
            for (int ii = 0; ii < 4; ++ii) {
                int d = wave * 32 + ii * 8 + dl;
                int chs = vch ^ (d & 7);
                const _Float16* g = Vtf + ((size_t)h * HD + d) * SEQQ + j0 + chs * 8;
                GLD16(g, &Vs[(wave * 32 + ii * 8) * 64]);
            }
        }
        __syncthreads();                 // K and V resident

        // ---- S = Q K^T (exp2 domain) ----
        f32x4 sacc[4];
#pragma unroll
        for (int n = 0; n < 4; ++n) sacc[n] = (f32x4){0.f, 0.f, 0.f, 0.f};
        __builtin_amdgcn_s_setprio(1);
#pragma unroll
        for (int c = 0; c < 4; ++c) {
#pragma unroll
            for (int n = 0; n < 4; ++n) {
                int row = n * 16 + lr;
                int chs = (4 * c + lq) ^ (lr & 7);
                f16x8 kf8 = *(const f16x8*)&Ks[row * 128 + chs * 8];
                sacc[n] = __builtin_amdgcn_mfma_f32_16x16x32_f16(qh[c], kf8, sacc[n], 0, 0, 0);
            }
        }
        __builtin_amdgcn_s_setprio(0);

        // ---- scale2 + causal mask + online softmax (exp2) ----
#pragma unroll
        for (int j = 0; j < 4; ++j) {
            const int grow = q0 + wave * 16 + lq * 4 + j;
#pragma unroll
            for (int n = 0; n < 4; ++n) {
                int gcol = j0 + n * 16 + lr;
                float val = sacc[n][j] * scale2;
                sacc[n][j] = (gcol > grow) ? -INFINITY : val;
            }
            float mx = fmaxf(fmaxf(sacc[0][j], sacc[1][j]), fmaxf(sacc[2][j], sacc[3][j]));
            mx = fmaxf(mx, __shfl_xor(mx, 1));
            mx = fmaxf(mx, __shfl_xor(mx, 2));
            mx = fmaxf(mx, __shfl_xor(mx, 4));
            mx = fmaxf(mx, __shfl_xor(mx, 8));
            float mn = fmaxf(m_run[j], mx);
            float corr = exp2f(m_run[j] - mn);   // 0 on first tile
            m_run[j] = mn;
            float ls = 0.f;
#pragma unroll
            for (int n = 0; n < 4; ++n) {
                float p = exp2f(sacc[n][j] - mn);
                Psh[wave][lq * 4 + j][n * 16 + lr] = (_Float16)p;
                ls += p;
            }
            ls += __shfl_xor(ls, 1);
            ls += __shfl_xor(ls, 2);
            ls += __shfl_xor(ls, 4);
            ls += __shfl_xor(ls, 8);
            l_run[j] = l_run[j] * corr + ls;
#pragma unroll
            for (int n = 0; n < 8; ++n) accO[n][j] *= corr;
        }

        // Psh is wave-private: same-wave write->read needs only lgkmcnt drain
        asm volatile("s_waitcnt lgkmcnt(0)" ::: "memory");

        // ---- PV: out += P V ----
        __builtin_amdgcn_s_setprio(1);
#pragma unroll
        for (int jc = 0; jc < 2; ++jc) {
            f16x8 pa = *(const f16x8*)&Psh[wave][lr][jc * 32 + lq * 8];
#pragma unroll
            for (int n = 0; n < 8; ++n) {
                int row = n * 16 + lr;
                int chv = (jc * 4 + lq) ^ (lr & 7);
                f16x8 vf = *(const f16x8*)&Vs[row * 64 + chv * 8];
                accO[n] = __builtin_amdgcn_mfma_f32_16x16x32_f16(pa, vf, accO[n], 0, 0, 0);
            }
        }
        __builtin_amdgcn_s_setprio(0);
    }

    // ---- normalize token part ----
#pragma unroll
    for (int j = 0; j < 4; ++j) {
        float inv_l = 1.0f / l_run[j];
#pragma unroll
        for (int n = 0; n < 8; ++n) accO[n][j] *= inv_l;
    }

    // ---- gated prefix (fp16 adapter K/V rows) ----
    {
        float g = tanhf(gate[h]);
        float sp[PLEN];
        float mp = -INFINITY;
#pragma unroll
        for (int i = 0; i < PLEN; ++i) {
            const _Float16* kpr = kp + (size_t)i * QKVLD + h * HD;
            float s = 0.f;
#pragma unroll
            for (int c = 0; c < 4; ++c)
#pragma unroll
                for (int e = 0; e < 8; ++e)
                    s = fmaf((float)qh[c][e], (float)kpr[c * 32 + lq * 8 + e], s);
            s += __shfl_xor(s, 16);
            s += __shfl_xor(s, 32);
            sp[i] = s * scale;
            mp = fmaxf(mp, sp[i]);
        }
        float ssum = 0.f;
#pragma unroll
        for (int i = 0; i < PLEN; ++i) { sp[i] = expf(sp[i] - mp); ssum += sp[i]; }
        float gs = g / ssum;
        if (lq == 0) {
#pragma unroll
            for (int i = 0; i < PLEN; ++i) Pp[wave][lr][i] = sp[i] * gs;
        }
        asm volatile("s_waitcnt lgkmcnt(0)" ::: "memory");
#pragma unroll
        for (int i = 0; i < PLEN; ++i) {
            float vv[8];
#pragma unroll
            for (int n = 0; n < 8; ++n)
                vv[n] = (float)vp[(size_t)i * QKVLD + h * HD + n * 16 + lr];
#pragma unroll
            for (int j = 0; j < 4; ++j) {
                float w = Pp[wave][lq * 4 + j][i];
#pragma unroll
                for (int n = 0; n < 8; ++n) accO[n][j] = fmaf(w, vv[n], accO[n][j]);
            }
        }
    }

    // ---- store fp16 output ----
#pragma unroll
    for (int n = 0; n < 8; ++n)
#pragma unroll
        for (int j = 0; j < 4; ++j)
            out[(size_t)(q0 + wave * 16 + lq * 4 + j) * HIDDEN + h * HD + n * 16 + lr] =
                (_Float16)accO[n][j];
}

// ================= fp32 fallback path (ws too small) =================
__global__ __launch_bounds__(256) void gemm_nt_kernel(
    const float* __restrict__ A, const float* __restrict__ B, float* __restrict__ C,
    int M, int N, int K)
{
    __shared__ float As[8][132];
    __shared__ float Bs[8][132];
    const int tid = threadIdx.x;
    const int tx = tid & 15, ty = tid >> 4;
    const int m0 = blockIdx.y * 128, n0 = blockIdx.x * 128;
    const int lr = tid >> 1;
    const int lk = (tid & 1) * 4;
    const bool aval = (m0 + lr) < M;
    const float* Ap = A + (size_t)(m0 + lr) * K + lk;
    const float* Bp = B + (size_t)(n0 + lr) * K + lk;

    float acc[8][8];
#pragma unroll
    for (int i = 0; i < 8; ++i)
#pragma unroll
        for (int j = 0; j < 8; ++j) acc[i][j] = 0.0f;

    for (int k0 = 0; k0 < K; k0 += 8) {
        float4 a4 = make_float4(0.f, 0.f, 0.f, 0.f);
        if (aval) a4 = *(const float4*)(Ap + k0);
        float4 b4 = *(const float4*)(Bp + k0);
        __syncthreads();
        As[lk + 0][lr] = a4.x; As[lk + 1][lr] = a4.y; As[lk + 2][lr] = a4.z; As[lk + 3][lr] = a4.w;
        Bs[lk + 0][lr] = b4.x; Bs[lk + 1][lr] = b4.y; Bs[lk + 2][lr] = b4.z; Bs[lk + 3][lr] = b4.w;
        __syncthreads();
#pragma unroll
        for (int kk = 0; kk < 8; ++kk) {
            float4 a0 = *(const float4*)&As[kk][ty * 8];
            float4 a1 = *(const float4*)&As[kk][ty * 8 + 4];
            float4 b0 = *(const float4*)&Bs[kk][tx * 8];
            float4 b1 = *(const float4*)&Bs[kk][tx * 8 + 4];
            float a[8] = {a0.x, a0.y, a0.z, a0.w, a1.x, a1.y, a1.z, a1.w};
            float b[8] = {b0.x, b0.y, b0.z, b0.w, b1.x, b1.y, b1.z, b1.w};
#pragma unroll
            for (int i = 0; i < 8; ++i)
#pragma unroll
                for (int j = 0; j < 8; ++j)
                    acc[i][j] = fmaf(a[i], b[j], acc[i][j]);
        }
    }
#pragma unroll
    for (int i = 0; i < 8; ++i) {
        int row = m0 + ty * 8 + i;
        if (row < M) {
            float* Cp = C + (size_t)row * N + n0 + tx * 8;
            *(float4*)Cp       = make_float4(acc[i][0], acc[i][1], acc[i][2], acc[i][3]);
            *(float4*)(Cp + 4) = make_float4(acc[i][4], acc[i][5], acc[i][6], acc[i][7]);
        }
    }
}

__global__ void rope_apply_kernel(float* __restrict__ q, float* __restrict__ k,
                                  const float* __restrict__ cosT, const float* __restrict__ sinT)
{
    int idx = blockIdx.x * 256 + threadIdx.x;
    int s = idx >> 11;
    int rem = idx & 2047;
    int h = rem >> 6;
    int d = rem & 63;
    float c = cosT[s * 64 + d], sn = sinT[s * 64 + d];
    size_t base = (size_t)s * HIDDEN + h * HD + d;
    float a = q[base], b = q[base + 64];
    q[base]      = a * c - b * sn;
    q[base + 64] = b * c + a * sn;
    a = k[base]; b = k[base + 64];
    k[base]      = a * c - b * sn;
    k[base + 64] = b * c + a * sn;
}

__global__ __launch_bounds__(256) void attn_kernel(
    const float* __restrict__ q, const float* __restrict__ k, const float* __restrict__ v,
    const float* __restrict__ kp, const float* __restrict__ vp,
    const float* __restrict__ gate, float* __restrict__ out)
{
    __shared__ float Qt[128][36];
    __shared__ float KV[128 * 68];
    __shared__ float Psh2[QT][68];

    const int h = blockIdx.y;
    const int r0 = blockIdx.x * QT;
    const int tid = threadIdx.x;
    const int orow = tid >> 3;
    const int oc4 = (tid & 7) * 4;
    const int sy = tid >> 4;
    const int sx = tid & 15;
    const float scale = 0.088388347648318447f;

#pragma unroll
    for (int i = 0; i < 4; ++i) {
        int flat = tid + 256 * i;
        int r = flat >> 5;
        int d = (flat & 31) << 2;
        float4 t = *(const float4*)(q + (size_t)(r0 + r) * HIDDEN + h * HD + d);
        Qt[d + 0][r] = t.x; Qt[d + 1][r] = t.y; Qt[d + 2][r] = t.z; Qt[d + 3][r] = t.w;
    }

    float acc[4][4];
#pragma unroll
    for (int u = 0; u < 4; ++u)
#pragma unroll
        for (int i = 0; i < 4; ++i) acc[u][i] = 0.0f;
    float m_run = -INFINITY, l_run = 0.0f;

    const int jb_max = (r0 + QT - 1) >> 6;
    for (int jb = 0; jb <= jb_max; ++jb) {
        const int j0 = jb * KT;
        __syncthreads();
#pragma unroll
        for (int i = 0; i < 8; ++i) {
            int flat = tid + 256 * i;
            int r = flat >> 5;
            int d = (flat & 31) << 2;
            float4 t = *(const float4*)(k + (size_t)(j0 + r) * HIDDEN + h * HD + d);
            KV[(d + 0) * 68 + r] = t.x; KV[(d + 1) * 68 + r] = t.y;
            KV[(d + 2) * 68 + r] = t.z; KV[(d + 3) * 68 + r] = t.w;
        }
        __syncthreads();
        float s8[2][4] = {{0.f, 0.f, 0.f, 0.f}, {0.f, 0.f, 0.f, 0.f}};
        for (int d = 0; d < 128; ++d) {
            float2 qv = *(const float2*)&Qt[d][sy * 2];
            float4 kv4 = *(const float4*)&KV[d * 68 + sx * 4];
            s8[0][0] = fmaf(qv.x, kv4.x, s8[0][0]);
            s8[0][1] = fmaf(qv.x, kv4.y, s8[0][1]);
            s8[0][2] = fmaf(qv.x, kv4.z, s8[0][2]);
            s8[0][3] = fmaf(qv.x, kv4.w, s8[0][3]);
            s8[1][0] = fmaf(qv.y, kv4.x, s8[1][0]);
            s8[1][1] = fmaf(qv.y, kv4.y, s8[1][1]);
            s8[1][2] = fmaf(qv.y, kv4.z, s8[1][2]);
            s8[1][3] = fmaf(qv.y, kv4.w, s8[1][3]);
        }
#pragma unroll
        for (int i = 0; i < 2; ++i) {
            int gr = r0 + sy * 2 + i;
#pragma unroll
            for (int jj = 0; jj < 4; ++jj) {
                int gj = j0 + sx * 4 + jj;
                float val = s8[i][jj] * scale;
                Psh2[sy * 2 + i][sx * 4 + jj] = (gj > gr) ? -INFINITY : val;
            }
        }
        __syncthreads();
        {
            const int c0 = (tid & 7) * 8;
            float sv[8];
            float mx = -INFINITY;
#pragma unroll
            for (int i = 0; i < 8; ++i) { sv[i] = Psh2[orow][c0 + i]; mx = fmaxf(mx, sv[i]); }
            mx = fmaxf(mx, __shfl_xor(mx, 1));
            mx = fmaxf(mx, __shfl_xor(mx, 2));
            mx = fmaxf(mx, __shfl_xor(mx, 4));
            float m_new = fmaxf(m_run, mx);
            float corr = expf(m_run - m_new);
            float lsum = 0.f;
#pragma unroll
            for (int i = 0; i < 8; ++i) {
                float p = expf(sv[i] - m_new);
                Psh2[orow][c0 + i] = p;
                lsum += p;
            }
            lsum += __shfl_xor(lsum, 1);
            lsum += __shfl_xor(lsum, 2);
            lsum += __shfl_xor(lsum, 4);
            l_run = l_run * corr + lsum;
            m_run = m_new;
#pragma unroll
            for (int u = 0; u < 4; ++u)
#pragma unroll
                for (int i = 0; i < 4; ++i) acc[u][i] *= corr;
        }
        __syncthreads();
#pragma unroll
        for (int i = 0; i < 8; ++i) {
            int flat = tid + 256 * i;
            int r = flat >> 5;
            int d = (flat & 31) << 2;
            float4 t = *(const float4*)(v + (size_t)(j0 + r) * HIDDEN + h * HD + d);
            *(float4*)&KV[r * 136 + d] = t;
        }
        __syncthreads();
        for (int j = 0; j < KT; ++j) {
            float p = Psh2[orow][j];
#pragma unroll
            for (int u = 0; u < 4; ++u) {
                float4 vv = *(const float4*)&KV[j * 136 + oc4 + u * 32];
                acc[u][0] = fmaf(p, vv.x, acc[u][0]);
                acc[u][1] = fmaf(p, vv.y, acc[u][1]);
                acc[u][2] = fmaf(p, vv.z, acc[u][2]);
                acc[u][3] = fmaf(p, vv.w, acc[u][3]);
            }
        }
    }

    float inv_l = 1.0f / l_run;
#pragma unroll
    for (int u = 0; u < 4; ++u)
#pragma unroll
        for (int i = 0; i < 4; ++i) acc[u][i] *= inv_l;

    {
        float g = tanhf(gate[h]);
        float sp[PLEN];
        float mp = -INFINITY;
#pragma unroll
        for (int i = 0; i < PLEN; ++i) {
            const float* kpr = kp + (size_t)i * HIDDEN + h * HD;
            float s = 0.f;
            for (int d = 0; d < 128; ++d) s = fmaf(Qt[d][orow], kpr[d], s);
            sp[i] = s * scale;
            mp = fmaxf(mp, sp[i]);
        }
        float ssum = 0.f;
#pragma unroll
        for (int i = 0; i < PLEN; ++i) { sp[i] = expf(sp[i] - mp); ssum += sp[i]; }
        float gs = g / ssum;
#pragma unroll
        for (int i = 0; i < PLEN; ++i) {
            float w = sp[i] * gs;
            const float* vpr = vp + (size_t)i * HIDDEN + h * HD;
#pragma unroll
            for (int u = 0; u < 4; ++u) {
                float4 vv = *(const float4*)(vpr + oc4 + u * 32);
                acc[u][0] = fmaf(w, vv.x, acc[u][0]);
                acc[u][1] = fmaf(w, vv.y, acc[u][1]);
                acc[u][2] = fmaf(w, vv.z, acc[u][2]);
                acc[u][3] = fmaf(w, vv.w, acc[u][3]);
            }
        }
    }

    float* op = out + (size_t)(r0 + orow) * HIDDEN + h * HD;
#pragma unroll
    for (int u = 0; u < 4; ++u)
        *(float4*)(op + oc4 + u * 32) = make_float4(acc[u][0], acc[u][1], acc[u][2], acc[u][3]);
}

extern "C" void kernel_launch(void* const* d_in, const int* in_sizes, int n_in,
                              void* d_out, int out_size, void* d_ws, size_t ws_size,
                              hipStream_t stream)
{
    (void)in_sizes; (void)n_in; (void)out_size;
    const float* hidden  = (const float*)d_in[0];
    const int*   pos     = (const int*)d_in[2];
    const float* Wq      = (const float*)d_in[3];
    const float* Wk      = (const float*)d_in[4];
    const float* Wv      = (const float*)d_in[5];
    const float* Wo      = (const float*)d_in[6];
    const float* adapter = (const float*)d_in[7];
    const float* gate    = (const float*)d_in[8];
    float* out = (float*)d_out;

    const size_t SH = (size_t)SEQQ * HIDDEN;          // 8,388,608
    const size_t WN = (size_t)HIDDEN * HIDDEN;        // 16,777,216
    const size_t PN = (size_t)128 * HIDDEN;           // 524,288
    const size_t QN = (size_t)MROWS * QKVLD;          // merged-GEMM output rows

    // ---- fp16 path layout: A = [Hf; Pf] contiguous (2176 x 4096) ----
    float* cosT = (float*)d_ws;
    float* sinT = cosT + (size_t)SEQQ * 64;
    _Float16* Hf    = (_Float16*)(sinT + (size_t)SEQQ * 64);   // SH
    _Float16* Pf    = Hf + SH;                        // PN (contiguous after Hf)
    _Float16* Wqkvf = Pf + PN;                        // 3*WN
    _Float16* QKVf  = Wqkvf + 3 * WN;                 // QN
    _Float16* Vtf   = QKVf + QN;                      // SH
    const size_t need = (size_t)((char*)(Vtf + SH) - (char*)d_ws);
    const bool use_f16 = (ws_size >= need);

    _Float16* Of  = Hf;                               // attn out overlays Hf (dead)
    _Float16* Wof = Wqkvf;                            // Wo fp16 overlays Wqkvf (dead)
    const _Float16* kpv = QKVf + (size_t)SEQQ * QKVLD;   // adapter proj rows (fp16)

    rope_table_kernel<<<SEQQ, 64, 0, stream>>>(pos, cosT, sinT);

    dim3 blk(256);
    const int nH8 = (int)(SH / 8);
    const int nW8 = (int)(WN / 8);

    if (use_f16) {
        cvt_f16_kernel<<<nH8 / 256, blk, 0, stream>>>(hidden, Hf, nH8);
        cvt_pad_f16_kernel<<<(int)(PN / 8 / 256), blk, 0, stream>>>(adapter, Pf);
        cvt3_f16_kernel<<<3 * nW8 / 256, blk, 0, stream>>>(Wq, Wk, Wv, Wqkvf);

        // merged QKV + adapter projection: [2176][4096] x [12288][4096]^T -> fp16
        // (gy=16 M-major walk for the 1536 QKV blocks + 96 adapter tail blocks)
        gemm_f16_kernel<_Float16><<<dim3(QKVLD / 128, 17), blk, 0, stream>>>(
            Hf, Wqkvf, QKVf, QKVLD, HIDDEN, MROWS);

        rope_vtrans_kernel<<<dim3(SEQQ / 64, NH), blk, 0, stream>>>(QKVf, cosT, sinT, Vtf);

        attn_f16_kernel<<<dim3(NH, SEQQ / 64), blk, 0, stream>>>(
            QKVf, QKVf + HIDDEN, Vtf, kpv + HIDDEN, kpv + 2 * HIDDEN, gate, Of);

        cvt_f16_kernel<<<nW8 / 256, blk, 0, stream>>>(Wo, Wof, nW8);
        gemm_f16_kernel<float><<<dim3(HIDDEN / 128, SEQQ / 128), blk, 0, stream>>>(
            Of, Wof, out, HIDDEN, HIDDEN, SEQQ);
    } else {
        // fp32 fallback
        float* ws = (float*)d_ws;
        float* qb   = ws;
        float* kb   = ws + SH;
        float* vb   = ws + 2 * SH;
        float* kpb  = ws + 3 * SH;
        float* vpb  = kpb + (size_t)PLEN * HIDDEN;
        float* cT   = vpb + (size_t)PLEN * HIDDEN;
        float* sT   = cT + (size_t)SEQQ * 64;
        rope_table_kernel<<<SEQQ, 64, 0, stream>>>(pos, cT, sT);
        dim3 gbig(HIDDEN / 128, SEQQ / 128);
        dim3 gsm(HIDDEN / 128, 1);
        gemm_nt_kernel<<<gbig, blk, 0, stream>>>(hidden, Wq, qb, SEQQ, HIDDEN, HIDDEN);
        gemm_nt_kernel<<<gbig, blk, 0, stream>>>(hidden, Wk, kb, SEQQ, HIDDEN, HIDDEN);
        gemm_nt_kernel<<<gbig, blk, 0, stream>>>(hidden, Wv, vb, SEQQ, HIDDEN, HIDDEN);
        gemm_nt_kernel<<<gsm, blk, 0, stream>>>(adapter, Wk, kpb, PLEN, HIDDEN, HIDDEN);
        gemm_nt_kernel<<<gsm, blk, 0, stream>>>(adapter, Wv, vpb, PLEN, HIDDEN, HIDDEN);
        rope_apply_kernel<<<(SEQQ * 2048) / 256, 256, 0, stream>>>(qb, kb, cT, sT);
        attn_kernel<<<dim3(SEQQ / QT, NH), blk, 0, stream>>>(qb, kb, vb, kpb, vpb, gate, qb);
        gemm_nt_kernel<<<gbig, blk, 0, stream>>>(qb, Wo, out, SEQQ, HIDDEN, HIDDEN);
    }
}

// Round 22
// 543.228 us; speedup vs baseline: 1.0196x; 1.0196x over previous
//
#include <hip/hip_runtime.h>
#include <math.h>

#define HIDDEN 4096
#define NH 32
#define HD 128
#define PLEN 10
#define SEQQ 2048
#define QT 32
#define KT 64
#define QKVLD 12288
#define MROWS 2176   // 2048 hidden rows + 128 padded adapter rows

typedef __attribute__((ext_vector_type(8))) _Float16 f16x8;
typedef __attribute__((ext_vector_type(4))) float f32x4;

// async global->LDS, 16 bytes per lane; LDS dest is wave-uniform base + lane*16
#define GLD16(g, l) __builtin_amdgcn_global_load_lds( \
        (const __attribute__((address_space(1))) void*)(g), \
        (__attribute__((address_space(3))) void*)(l), 16, 0, 0)

// ---------------- fp32 -> fp16 plane, 8 elems/thread ----------------
__global__ __launch_bounds__(256) void cvt_f16_kernel(
    const float* __restrict__ x, _Float16* __restrict__ y, int n8)
{
    int idx = blockIdx.x * 256 + threadIdx.x;
    if (idx >= n8) return;
    const float4* xp = (const float4*)x;
    float4 a = xp[idx * 2], b = xp[idx * 2 + 1];
    f16x8 o;
    o[0] = (_Float16)a.x; o[1] = (_Float16)a.y; o[2] = (_Float16)a.z; o[3] = (_Float16)a.w;
    o[4] = (_Float16)b.x; o[5] = (_Float16)b.y; o[6] = (_Float16)b.z; o[7] = (_Float16)b.w;
    *(f16x8*)(y + (size_t)idx * 8) = o;
}

// ---------------- 3 x fp32 weight -> contiguous fp16 (one launch) ----------------
__global__ __launch_bounds__(256) void cvt3_f16_kernel(
    const float* __restrict__ w0, const float* __restrict__ w1, const float* __restrict__ w2,
    _Float16* __restrict__ y)
{
    int idx = blockIdx.x * 256 + threadIdx.x;       // < 3 * 2^21
    int sel = idx >> 21;
    int off = idx & ((1 << 21) - 1);
    const float* src = (sel == 0) ? w0 : (sel == 1) ? w1 : w2;
    const float4* xp = (const float4*)src;
    float4 a = xp[off * 2], b = xp[off * 2 + 1];
    f16x8 o;
    o[0] = (_Float16)a.x; o[1] = (_Float16)a.y; o[2] = (_Float16)a.z; o[3] = (_Float16)a.w;
    o[4] = (_Float16)b.x; o[5] = (_Float16)b.y; o[6] = (_Float16)b.z; o[7] = (_Float16)b.w;
    *(f16x8*)(y + (size_t)idx * 8) = o;
}

// ---------------- adapter (10x4096) -> zero-padded 128x4096 fp16 ----------------
__global__ __launch_bounds__(256) void cvt_pad_f16_kernel(
    const float* __restrict__ src, _Float16* __restrict__ y)
{
    int idx = blockIdx.x * 256 + threadIdx.x;
    int row = idx >> 9;
    f16x8 o;
    if (row < PLEN) {
        const float4* xp = (const float4*)src;
        float4 a = xp[idx * 2], b = xp[idx * 2 + 1];
        o[0] = (_Float16)a.x; o[1] = (_Float16)a.y; o[2] = (_Float16)a.z; o[3] = (_Float16)a.w;
        o[4] = (_Float16)b.x; o[5] = (_Float16)b.y; o[6] = (_Float16)b.z; o[7] = (_Float16)b.w;
    } else {
#pragma unroll
        for (int i = 0; i < 8; ++i) o[i] = (_Float16)0.0f;
    }
    *(f16x8*)(y + (size_t)idx * 8) = o;
}

// ---------------- fp16 MFMA GEMM NT, 128x128, counted-vmcnt double-buffer (R13) ----------------
template <typename OT>
__global__ __launch_bounds__(256) void gemm_f16_kernel(
    const _Float16* __restrict__ A, const _Float16* __restrict__ B,
    OT* __restrict__ C, int N, int K, int Mstore)
{
    __shared__ _Float16 lds[2 * 16384];   // [dbuf][A plane 8192 | B plane 8192]

    const int tid = threadIdx.x;
    const int lane = tid & 63;
    const int wave = tid >> 6;

    // XCD-aware bijective swizzle, then M-major walk (consecutive sw share B panel)
    const int gx = gridDim.x;
    const int gy = gridDim.y;
    const int nwg = gx * gy;
    const int flat = blockIdx.y * gx + blockIdx.x;
    const int cpx = nwg >> 3;
    const int sw = (flat & 7) * cpx + (flat >> 3);
    const int m0 = (sw % gy) * 128;
    const int n0 = (sw / gy) * 128;

    const _Float16* srcp = (wave < 2) ? A : B;
    const int tb = ((wave < 2) ? m0 : n0) + (wave & 1) * 64;
    const int swz = ((lane & 7) ^ ((lane >> 3) & 7)) << 3;   // pre-swizzled global col
    const _Float16* p0 = srcp + (size_t)(tb + (lane >> 3)) * K + swz;
    const int ldso = (wave >> 1) * 8192 + (wave & 1) * 4096;

    const int lr = lane & 15;
    const int lq = lane >> 4;
    const int wm = (wave >> 1) * 64;
    const int wn = (wave & 1) * 64;

    f32x4 acc[4][4];
#pragma unroll
    for (int m = 0; m < 4; ++m)
#pragma unroll
        for (int n = 0; n < 4; ++n) acc[m][n] = (f32x4){0.f, 0.f, 0.f, 0.f};

#define STAGE(bufsel, tt) do { \
        _Float16* dst_ = &lds[(bufsel) * 16384 + ldso]; \
        const _Float16* src_ = p0 + ((size_t)(tt) << 6); \
        GLD16(src_ + 0 * 8 * (size_t)K, dst_ + 0 * 512); \
        GLD16(src_ + 1 * 8 * (size_t)K, dst_ + 1 * 512); \
        GLD16(src_ + 2 * 8 * (size_t)K, dst_ + 2 * 512); \
        GLD16(src_ + 3 * 8 * (size_t)K, dst_ + 3 * 512); \
        GLD16(src_ + 4 * 8 * (size_t)K, dst_ + 4 * 512); \
        GLD16(src_ + 5 * 8 * (size_t)K, dst_ + 5 * 512); \
        GLD16(src_ + 6 * 8 * (size_t)K, dst_ + 6 * 512); \
        GLD16(src_ + 7 * 8 * (size_t)K, dst_ + 7 * 512); \
    } while (0)

    const int NK = K >> 6;      // >= 2 for all our shapes (K = 4096)
    STAGE(0, 0);
    STAGE(1, 1);

    for (int t = 0; t < NK; ++t) {
        const int cur = t & 1;
        if (t == NK - 1) asm volatile("s_waitcnt vmcnt(0)" ::: "memory");
        else             asm volatile("s_waitcnt vmcnt(8)" ::: "memory");
        __builtin_amdgcn_s_barrier();     // collective: tile t resident for all waves

        const _Float16* la = &lds[cur * 16384];
        const _Float16* lb = &lds[cur * 16384 + 8192];
#pragma unroll
        for (int kc = 0; kc < 2; ++kc) {
            f16x8 af[4], bf[4];
#pragma unroll
            for (int m = 0; m < 4; ++m) {
                int r = wm + m * 16 + lr;
                af[m] = *(const f16x8*)&la[(r << 6) + ((((kc << 2) + lq) ^ (lr & 7)) << 3)];
            }
#pragma unroll
            for (int n = 0; n < 4; ++n) {
                int r = wn + n * 16 + lr;
                bf[n] = *(const f16x8*)&lb[(r << 6) + ((((kc << 2) + lq) ^ (lr & 7)) << 3)];
            }
            __builtin_amdgcn_s_setprio(1);
#pragma unroll
            for (int m = 0; m < 4; ++m)
#pragma unroll
                for (int n = 0; n < 4; ++n)
                    acc[m][n] = __builtin_amdgcn_mfma_f32_16x16x32_f16(af[m], bf[n], acc[m][n], 0, 0, 0);
            __builtin_amdgcn_s_setprio(0);
        }
        __builtin_amdgcn_s_barrier();     // all waves done reading buf[cur]
        if (t + 2 < NK) STAGE(cur, t + 2);
    }
#undef STAGE

    // C layout: col = lane&15, row = (lane>>4)*4 + j
#pragma unroll
    for (int m = 0; m < 4; ++m) {
        const int row = m0 + wm + m * 16 + lq * 4;
#pragma unroll
        for (int n = 0; n < 4; ++n) {
            const int col = n0 + wn + n * 16 + lr;
#pragma unroll
            for (int j = 0; j < 4; ++j)
                if (row + j < Mstore)
                    C[(size_t)(row + j) * N + col] = (OT)acc[m][n][j];
        }
    }
}

// ---------------- RoPE cos/sin tables ----------------
__global__ void rope_table_kernel(const int* __restrict__ pos,
                                  float* __restrict__ cosT, float* __restrict__ sinT)
{
    int s = blockIdx.x;
    int j = threadIdx.x;               // 0..63
    float p = (float)pos[s];
    float expnt = (2.0f * (float)j) * (1.0f / 128.0f);
    float inv_freq = powf(10000.0f, -expnt);
    float f = p * inv_freq;
    cosT[s * 64 + j] = cosf(f);
    sinT[s * 64 + j] = sinf(f);
}

// ---------------- fused: RoPE (Q,K in place) + V -> Vt transpose ----------------
__global__ __launch_bounds__(256) void rope_vtrans_kernel(
    _Float16* __restrict__ qkv, const float* __restrict__ cosT, const float* __restrict__ sinT,
    _Float16* __restrict__ vt)
{
    __shared__ _Float16 Vsh[64][136];
    const int h = blockIdx.y;
    const int s0 = blockIdx.x * 64;
    const int tid = threadIdx.x;

    // ---- V tile load (for transpose) ----
#pragma unroll
    for (int i = 0; i < 4; ++i) {
        int flat = tid + 256 * i;          // 0..1023
        int r = flat >> 4;
        int c8 = (flat & 15) * 8;
        *(f16x8*)&Vsh[r][c8] =
            *(const f16x8*)(qkv + (size_t)(s0 + r) * QKVLD + 2 * HIDDEN + h * HD + c8);
    }

    // ---- RoPE on Q and K rows of this (s-tile, head) ----
#pragma unroll
    for (int i = 0; i < 16; ++i) {
        int flat = tid + 256 * i;          // 0..4095
        int r = flat >> 6;                 // 0..63
        int d = flat & 63;
        int s = s0 + r;
        float c = cosT[s * 64 + d], sn = sinT[s * 64 + d];
        size_t base = (size_t)s * QKVLD + h * HD + d;
        float a = (float)qkv[base], b = (float)qkv[base + 64];
        qkv[base]      = (_Float16)(a * c - b * sn);
        qkv[base + 64] = (_Float16)(b * c + a * sn);
        size_t kb = base + HIDDEN;
        a = (float)qkv[kb]; b = (float)qkv[kb + 64];
        qkv[kb]      = (_Float16)(a * c - b * sn);
        qkv[kb + 64] = (_Float16)(b * c + a * sn);
    }

    __syncthreads();
    // ---- Vt store ----
#pragma unroll
    for (int pass = 0; pass < 4; ++pass) {
        int d = pass * 32 + (tid >> 3);
        int sb = (tid & 7) * 8;
        f16x8 o;
#pragma unroll
        for (int e = 0; e < 8; ++e) o[e] = Vsh[sb + e][d];
        *(f16x8*)(vt + ((size_t)h * HD + d) * SEQQ + s0 + sb) = o;
    }
}

// ---------------- MFMA fp16 flash attention, causal + gated prefix (R19 structure) ----------------
// grid (NH, 32): qt = 31 - blockIdx.y (longest-first). 2 barriers/tile.
__global__ __launch_bounds__(256) void attn_f16_kernel(
    const _Float16* __restrict__ Qf, const _Float16* __restrict__ Kf,
    const _Float16* __restrict__ Vtf,
    const _Float16* __restrict__ kp, const _Float16* __restrict__ vp,
    const float* __restrict__ gate, _Float16* __restrict__ out)
{
    __shared__ _Float16 Ks[64 * 128];    // 16KB K tile [j][128]
    __shared__ _Float16 Vs[128 * 64];    // 16KB Vt tile [d][64]
    __shared__ _Float16 Psh[4][16][72];  // P tile (f16) per wave (wave-private)
    __shared__ float Pp[4][16][12];      // gated prefix probs per wave

    const int h = blockIdx.x;
    const int qt = (gridDim.y - 1) - blockIdx.y;   // longest-first
    const int q0 = qt * 64;
    const int tid = threadIdx.x;
    const int wave = tid >> 6;
    const int lane = tid & 63;
    const int lr = lane & 15;
    const int lq = lane >> 4;
    const float scale = 0.088388347648318447f;                 // 1/sqrt(128)
    const float scale2 = 0.088388347648318447f * 1.4426950408889634f;  // *log2(e)

    const int qrow = q0 + wave * 16 + lr;
    f16x8 qh[4];
#pragma unroll
    for (int c = 0; c < 4; ++c)
        qh[c] = *(const f16x8*)(Qf + (size_t)qrow * QKVLD + h * HD + c * 32 + lq * 8);

    f32x4 accO[8];
#pragma unroll
    for (int n = 0; n < 8; ++n) accO[n] = (f32x4){0.f, 0.f, 0.f, 0.f};
    float m_run[4] = {-INFINITY, -INFINITY, -INFINITY, -INFINITY};
    float l_run[4] = {0.f, 0.f, 0.f, 0.f};

    const int ntiles = qt + 1;
    for (int t = 0; t < ntiles; ++t) {
        const int j0 = t * 64;
        __syncthreads();                 // prev tile's K/V reads done

        // ---- stage K tile (wave w -> rows 16w..16w+15) ----
        {
            const int rl = lane >> 4;
            const int ch = lane & 15;
#pragma unroll
            for (int ii = 0; ii < 4; ++ii) {
                int r = wave * 16 + ii * 4 + rl;
                int chs = ch ^ (r & 7);
                const _Float16* g = Kf + (size_t)(j0 + r) * QKVLD + h * HD + chs * 8;
                GLD16(g, &Ks[(wave * 16 + ii * 4) * 128]);
            }
        }
        // ---- stage Vt tile (wave w -> d rows 32w..32w+31) ----
        {
            const int dl = lane >> 3;
            const int vch = lane & 7;
#pragma unroll
            for (int ii = 0; ii < 4; ++ii) {
                int d = wave * 32 + ii * 8 + dl;
                int chs = vch ^ (d & 7);
                const _Float16* g = Vtf + ((size_t)h * HD + d) * SEQQ + j0 + chs * 8;
                GLD16(g, &Vs[(wave * 32 + ii * 8) * 64]);
            }
        }
        __syncthreads();                 // K and V resident

        // ---- S = Q K^T (exp2 domain) ----
        f32x4 sacc[4];
#pragma unroll
        for (int n = 0; n < 4; ++n) sacc[n] = (f32x4){0.f, 0.f, 0.f, 0.f};
        __builtin_amdgcn_s_setprio(1);
#pragma unroll
        for (int c = 0; c < 4; ++c) {
#pragma unroll
            for (int n = 0; n < 4; ++n) {
                int row = n * 16 + lr;
                int chs = (4 * c + lq) ^ (lr & 7);
                f16x8 kf8 = *(const f16x8*)&Ks[row * 128 + chs * 8];
                sacc[n] = __builtin_amdgcn_mfma_f32_16x16x32_f16(qh[c], kf8, sacc[n], 0, 0, 0);
            }
        }
        __builtin_amdgcn_s_setprio(0);

        // ---- scale2 + causal mask + online softmax (exp2) ----
#pragma unroll
        for (int j = 0; j < 4; ++j) {
            const int grow = q0 + wave * 16 + lq * 4 + j;
#pragma unroll
            for (int n = 0; n < 4; ++n) {
                int gcol = j0 + n * 16 + lr;
                float val = sacc[n][j] * scale2;
                sacc[n][j] = (gcol > grow) ? -INFINITY : val;
            }
            float mx = fmaxf(fmaxf(sacc[0][j], sacc[1][j]), fmaxf(sacc[2][j], sacc[3][j]));
            mx = fmaxf(mx, __shfl_xor(mx, 1));
            mx = fmaxf(mx, __shfl_xor(mx, 2));
            mx = fmaxf(mx, __shfl_xor(mx, 4));
            mx = fmaxf(mx, __shfl_xor(mx, 8));
            float mn = fmaxf(m_run[j], mx);
            float corr = exp2f(m_run[j] - mn);   // 0 on first tile
            m_run[j] = mn;
            float ls = 0.f;
#pragma unroll
            for (int n = 0; n < 4; ++n) {
                float p = exp2f(sacc[n][j] - mn);
                Psh[wave][lq * 4 + j][n * 16 + lr] = (_Float16)p;
                ls += p;
            }
            ls += __shfl_xor(ls, 1);
            ls += __shfl_xor(ls, 2);
            ls += __shfl_xor(ls, 4);
            ls += __shfl_xor(ls, 8);
            l_run[j] = l_run[j] * corr + ls;
#pragma unroll
            for (int n = 0; n < 8; ++n) accO[n][j] *= corr;
        }

        // Psh is wave-private: same-wave write->read needs only lgkmcnt drain
        asm volatile("s_waitcnt lgkmcnt(0)" ::: "memory");

        // ---- PV: out += P V ----
        __builtin_amdgcn_s_setprio(1);
#pragma unroll
        for (int jc = 0; jc < 2; ++jc) {
            f16x8 pa = *(const f16x8*)&Psh[wave][lr][jc * 32 + lq * 8];
#pragma unroll
            for (int n = 0; n < 8; ++n) {
                int row = n * 16 + lr;
                int chv = (jc * 4 + lq) ^ (lr & 7);
                f16x8 vf = *(const f16x8*)&Vs[row * 64 + chv * 8];
                accO[n] = __builtin_amdgcn_mfma_f32_16x16x32_f16(pa, vf, accO[n], 0, 0, 0);
            }
        }
        __builtin_amdgcn_s_setprio(0);
    }

    // ---- normalize token part ----
#pragma unroll
    for (int j = 0; j < 4; ++j) {
        float inv_l = 1.0f / l_run[j];
#pragma unroll
        for (int n = 0; n < 8; ++n) accO[n][j] *= inv_l;
    }

    // ---- gated prefix (fp16 adapter K/V rows) ----
    {
        float g = tanhf(gate[h]);
        float sp[PLEN];
        float mp = -INFINITY;
#pragma unroll
        for (int i = 0; i < PLEN; ++i) {
            const _Float16* kpr = kp + (size_t)i * QKVLD + h * HD;
            float s = 0.f;
#pragma unroll
            for (int c = 0; c < 4; ++c)
#pragma unroll
                for (int e = 0; e < 8; ++e)
                    s = fmaf((float)qh[c][e], (float)kpr[c * 32 + lq * 8 + e], s);
            s += __shfl_xor(s, 16);
            s += __shfl_xor(s, 32);
            sp[i] = s * scale;
            mp = fmaxf(mp, sp[i]);
        }
        float ssum = 0.f;
#pragma unroll
        for (int i = 0; i < PLEN; ++i) { sp[i] = expf(sp[i] - mp); ssum += sp[i]; }
        float gs = g / ssum;
        if (lq == 0) {
#pragma unroll
            for (int i = 0; i < PLEN; ++i) Pp[wave][lr][i] = sp[i] * gs;
        }
        asm volatile("s_waitcnt lgkmcnt(0)" ::: "memory");
#pragma unroll
        for (int i = 0; i < PLEN; ++i) {
            float vv[8];
#pragma unroll
            for (int n = 0; n < 8; ++n)
                vv[n] = (float)vp[(size_t)i * QKVLD + h * HD + n * 16 + lr];
#pragma unroll
            for (int j = 0; j < 4; ++j) {
                float w = Pp[wave][lq * 4 + j][i];
#pragma unroll
                for (int n = 0; n < 8; ++n) accO[n][j] = fmaf(w, vv[n], accO[n][j]);
            }
        }
    }

    // ---- store fp16 output ----
#pragma unroll
    for (int n = 0; n < 8; ++n)
#pragma unroll
        for (int j = 0; j < 4; ++j)
            out[(size_t)(q0 + wave * 16 + lq * 4 + j) * HIDDEN + h * HD + n * 16 + lr] =
                (_Float16)accO[n][j];
}

// ================= fp32 fallback path (ws too small) =================
__global__ __launch_bounds__(256) void gemm_nt_kernel(
    const float* __restrict__ A, const float* __restrict__ B, float* __restrict__ C,
    int M, int N, int K)
{
    __shared__ float As[8][132];
    __shared__ float Bs[8][132];
    const int tid = threadIdx.x;
    const int tx = tid & 15, ty = tid >> 4;
    const int m0 = blockIdx.y * 128, n0 = blockIdx.x * 128;
    const int lr = tid >> 1;
    const int lk = (tid & 1) * 4;
    const bool aval = (m0 + lr) < M;
    const float* Ap = A + (size_t)(m0 + lr) * K + lk;
    const float* Bp = B + (size_t)(n0 + lr) * K + lk;

    float acc[8][8];
#pragma unroll
    for (int i = 0; i < 8; ++i)
#pragma unroll
        for (int j = 0; j < 8; ++j) acc[i][j] = 0.0f;

    for (int k0 = 0; k0 < K; k0 += 8) {
        float4 a4 = make_float4(0.f, 0.f, 0.f, 0.f);
        if (aval) a4 = *(const float4*)(Ap + k0);
        float4 b4 = *(const float4*)(Bp + k0);
        __syncthreads();
        As[lk + 0][lr] = a4.x; As[lk + 1][lr] = a4.y; As[lk + 2][lr] = a4.z; As[lk + 3][lr] = a4.w;
        Bs[lk + 0][lr] = b4.x; Bs[lk + 1][lr] = b4.y; Bs[lk + 2][lr] = b4.z; Bs[lk + 3][lr] = b4.w;
        __syncthreads();
#pragma unroll
        for (int kk = 0; kk < 8; ++kk) {
            float4 a0 = *(const float4*)&As[kk][ty * 8];
            float4 a1 = *(const float4*)&As[kk][ty * 8 + 4];
            float4 b0 = *(const float4*)&Bs[kk][tx * 8];
            float4 b1 = *(const float4*)&Bs[kk][tx * 8 + 4];
            float a[8] = {a0.x, a0.y, a0.z, a0.w, a1.x, a1.y, a1.z, a1.w};
            float b[8] = {b0.x, b0.y, b0.z, b0.w, b1.x, b1.y, b1.z, b1.w};
#pragma unroll
            for (int i = 0; i < 8; ++i)
#pragma unroll
                for (int j = 0; j < 8; ++j)
                    acc[i][j] = fmaf(a[i], b[j], acc[i][j]);
        }
    }
#pragma unroll
    for (int i = 0; i < 8; ++i) {
        int row = m0 + ty * 8 + i;
        if (row < M) {
            float* Cp = C + (size_t)row * N + n0 + tx * 8;
            *(float4*)Cp       = make_float4(acc[i][0], acc[i][1], acc[i][2], acc[i][3]);
            *(float4*)(Cp + 4) = make_float4(acc[i][4], acc[i][5], acc[i][6], acc[i][7]);
        }
    }
}

__global__ void rope_apply_kernel(float* __restrict__ q, float* __restrict__ k,
                                  const float* __restrict__ cosT, const float* __restrict__ sinT)
{
    int idx = blockIdx.x * 256 + threadIdx.x;
    int s = idx >> 11;
    int rem = idx & 2047;
    int h = rem >> 6;
    int d = rem & 63;
    float c = cosT[s * 64 + d], sn = sinT[s * 64 + d];
    size_t base = (size_t)s * HIDDEN + h * HD + d;
    float a = q[base], b = q[base + 64];
    q[base]      = a * c - b * sn;
    q[base + 64] = b * c + a * sn;
    a = k[base]; b = k[base + 64];
    k[base]      = a * c - b * sn;
    k[base + 64] = b * c + a * sn;
}

__global__ __launch_bounds__(256) void attn_kernel(
    const float* __restrict__ q, const float* __restrict__ k, const float* __restrict__ v,
    const float* __restrict__ kp, const float* __restrict__ vp,
    const float* __restrict__ gate, float* __restrict__ out)
{
    __shared__ float Qt[128][36];
    __shared__ float KV[128 * 68];
    __shared__ float Psh2[QT][68];

    const int h = blockIdx.y;
    const int r0 = blockIdx.x * QT;
    const int tid = threadIdx.x;
    const int orow = tid >> 3;
    const int oc4 = (tid & 7) * 4;
    const int sy = tid >> 4;
    const int sx = tid & 15;
    const float scale = 0.088388347648318447f;

#pragma unroll
    for (int i = 0; i < 4; ++i) {
        int flat = tid + 256 * i;
        int r = flat >> 5;
        int d = (flat & 31) << 2;
        float4 t = *(const float4*)(q + (size_t)(r0 + r) * HIDDEN + h * HD + d);
        Qt[d + 0][r] = t.x; Qt[d + 1][r] = t.y; Qt[d + 2][r] = t.z; Qt[d + 3][r] = t.w;
    }

    float acc[4][4];
#pragma unroll
    for (int u = 0; u < 4; ++u)
#pragma unroll
        for (int i = 0; i < 4; ++i) acc[u][i] = 0.0f;
    float m_run = -INFINITY, l_run = 0.0f;

    const int jb_max = (r0 + QT - 1) >> 6;
    for (int jb = 0; jb <= jb_max; ++jb) {
        const int j0 = jb * KT;
        __syncthreads();
#pragma unroll
        for (int i = 0; i < 8; ++i) {
            int flat = tid + 256 * i;
            int r = flat >> 5;
            int d = (flat & 31) << 2;
            float4 t = *(const float4*)(k + (size_t)(j0 + r) * HIDDEN + h * HD + d);
            KV[(d + 0) * 68 + r] = t.x; KV[(d + 1) * 68 + r] = t.y;
            KV[(d + 2) * 68 + r] = t.z; KV[(d + 3) * 68 + r] = t.w;
        }
        __syncthreads();
        float s8[2][4] = {{0.f, 0.f, 0.f, 0.f}, {0.f, 0.f, 0.f, 0.f}};
        for (int d = 0; d < 128; ++d) {
            float2 qv = *(const float2*)&Qt[d][sy * 2];
            float4 kv4 = *(const float4*)&KV[d * 68 + sx * 4];
            s8[0][0] = fmaf(qv.x, kv4.x, s8[0][0]);
            s8[0][1] = fmaf(qv.x, kv4.y, s8[0][1]);
            s8[0][2] = fmaf(qv.x, kv4.z, s8[0][2]);
            s8[0][3] = fmaf(qv.x, kv4.w, s8[0][3]);
            s8[1][0] = fmaf(qv.y, kv4.x, s8[1][0]);
            s8[1][1] = fmaf(qv.y, kv4.y, s8[1][1]);
            s8[1][2] = fmaf(qv.y, kv4.z, s8[1][2]);
            s8[1][3] = fmaf(qv.y, kv4.w, s8[1][3]);
        }
#pragma unroll
        for (int i = 0; i < 2; ++i) {
            int gr = r0 + sy * 2 + i;
#pragma unroll
            for (int jj = 0; jj < 4; ++jj) {
                int gj = j0 + sx * 4 + jj;
                float val = s8[i][jj] * scale;
                Psh2[sy * 2 + i][sx * 4 + jj] = (gj > gr) ? -INFINITY : val;
            }
        }
        __syncthreads();
        {
            const int c0 = (tid & 7) * 8;
            float sv[8];
            float mx = -INFINITY;
#pragma unroll
            for (int i = 0; i < 8; ++i) { sv[i] = Psh2[orow][c0 + i]; mx = fmaxf(mx, sv[i]); }
            mx = fmaxf(mx, __shfl_xor(mx, 1));
            mx = fmaxf(mx, __shfl_xor(mx, 2));
            mx = fmaxf(mx, __shfl_xor(mx, 4));
            float m_new = fmaxf(m_run, mx);
            float corr = expf(m_run - m_new);
            float lsum = 0.f;
#pragma unroll
            for (int i = 0; i < 8; ++i) {
                float p = expf(sv[i] - m_new);
                Psh2[orow][c0 + i] = p;
                lsum += p;
            }
            lsum += __shfl_xor(lsum, 1);
            lsum += __shfl_xor(lsum, 2);
            lsum += __shfl_xor(lsum, 4);
            l_run = l_run * corr + lsum;
            m_run = m_new;
#pragma unroll
            for (int u = 0; u < 4; ++u)
#pragma unroll
                for (int i = 0; i < 4; ++i) acc[u][i] *= corr;
        }
        __syncthreads();
#pragma unroll
        for (int i = 0; i < 8; ++i) {
            int flat = tid + 256 * i;
            int r = flat >> 5;
            int d = (flat & 31) << 2;
            float4 t = *(const float4*)(v + (size_t)(j0 + r) * HIDDEN + h * HD + d);
            *(float4*)&KV[r * 136 + d] = t;
        }
        __syncthreads();
        for (int j = 0; j < KT; ++j) {
            float p = Psh2[orow][j];
#pragma unroll
            for (int u = 0; u < 4; ++u) {
                float4 vv = *(const float4*)&KV[j * 136 + oc4 + u * 32];
                acc[u][0] = fmaf(p, vv.x, acc[u][0]);
                acc[u][1] = fmaf(p, vv.y, acc[u][1]);
                acc[u][2] = fmaf(p, vv.z, acc[u][2]);
                acc[u][3] = fmaf(p, vv.w, acc[u][3]);
            }
        }
    }

    float inv_l = 1.0f / l_run;
#pragma unroll
    for (int u = 0; u < 4; ++u)
#pragma unroll
        for (int i = 0; i < 4; ++i) acc[u][i] *= inv_l;

    {
        float g = tanhf(gate[h]);
        float sp[PLEN];
        float mp = -INFINITY;
#pragma unroll
        for (int i = 0; i < PLEN; ++i) {
            const float* kpr = kp + (size_t)i * HIDDEN + h * HD;
            float s = 0.f;
            for (int d = 0; d < 128; ++d) s = fmaf(Qt[d][orow], kpr[d], s);
            sp[i] = s * scale;
            mp = fmaxf(mp, sp[i]);
        }
        float ssum = 0.f;
#pragma unroll
        for (int i = 0; i < PLEN; ++i) { sp[i] = expf(sp[i] - mp); ssum += sp[i]; }
        float gs = g / ssum;
#pragma unroll
        for (int i = 0; i < PLEN; ++i) {
            float w = sp[i] * gs;
            const float* vpr = vp + (size_t)i * HIDDEN + h * HD;
#pragma unroll
            for (int u = 0; u < 4; ++u) {
                float4 vv = *(const float4*)(vpr + oc4 + u * 32);
                acc[u][0] = fmaf(w, vv.x, acc[u][0]);
                acc[u][1] = fmaf(w, vv.y, acc[u][1]);
                acc[u][2] = fmaf(w, vv.z, acc[u][2]);
                acc[u][3] = fmaf(w, vv.w, acc[u][3]);
            }
        }
    }

    float* op = out + (size_t)(r0 + orow) * HIDDEN + h * HD;
#pragma unroll
    for (int u = 0; u < 4; ++u)
        *(float4*)(op + oc4 + u * 32) = make_float4(acc[u][0], acc[u][1], acc[u][2], acc[u][3]);
}

extern "C" void kernel_launch(void* const* d_in, const int* in_sizes, int n_in,
                              void* d_out, int out_size, void* d_ws, size_t ws_size,
                              hipStream_t stream)
{
    (void)in_sizes; (void)n_in; (void)out_size;
    const float* hidden  = (const float*)d_in[0];
    const int*   pos     = (const int*)d_in[2];
    const float* Wq      = (const float*)d_in[3];
    const float* Wk      = (const float*)d_in[4];
    const float* Wv      = (const float*)d_in[5];
    const float* Wo      = (const float*)d_in[6];
    const float* adapter = (const float*)d_in[7];
    const float* gate    = (const float*)d_in[8];
    float* out = (float*)d_out;

    const size_t SH = (size_t)SEQQ * HIDDEN;          // 8,388,608
    const size_t WN = (size_t)HIDDEN * HIDDEN;        // 16,777,216
    const size_t PN = (size_t)128 * HIDDEN;           // 524,288
    const size_t QN = (size_t)MROWS * QKVLD;          // merged-GEMM output rows

    // ---- fp16 path layout: A = [Hf; Pf] contiguous (2176 x 4096) ----
    float* cosT = (float*)d_ws;
    float* sinT = cosT + (size_t)SEQQ * 64;
    _Float16* Hf    = (_Float16*)(sinT + (size_t)SEQQ * 64);   // SH
    _Float16* Pf    = Hf + SH;                        // PN (contiguous after Hf)
    _Float16* Wqkvf = Pf + PN;                        // 3*WN
    _Float16* QKVf  = Wqkvf + 3 * WN;                 // QN
    _Float16* Vtf   = QKVf + QN;                      // SH
    const size_t need = (size_t)((char*)(Vtf + SH) - (char*)d_ws);
    const bool use_f16 = (ws_size >= need);

    _Float16* Of  = Hf;                               // attn out overlays Hf (dead)
    _Float16* Wof = Wqkvf;                            // Wo fp16 overlays Wqkvf (dead)
    const _Float16* kpv = QKVf + (size_t)SEQQ * QKVLD;   // adapter proj rows (fp16)

    rope_table_kernel<<<SEQQ, 64, 0, stream>>>(pos, cosT, sinT);

    dim3 blk(256);
    const int nH8 = (int)(SH / 8);
    const int nW8 = (int)(WN / 8);

    if (use_f16) {
        cvt_f16_kernel<<<nH8 / 256, blk, 0, stream>>>(hidden, Hf, nH8);
        cvt_pad_f16_kernel<<<(int)(PN / 8 / 256), blk, 0, stream>>>(adapter, Pf);
        cvt3_f16_kernel<<<3 * nW8 / 256, blk, 0, stream>>>(Wq, Wk, Wv, Wqkvf);

        // merged QKV + adapter projection: [2176][4096] x [12288][4096]^T -> fp16
        gemm_f16_kernel<_Float16><<<dim3(QKVLD / 128, MROWS / 128), blk, 0, stream>>>(
            Hf, Wqkvf, QKVf, QKVLD, HIDDEN, MROWS);

        rope_vtrans_kernel<<<dim3(SEQQ / 64, NH), blk, 0, stream>>>(QKVf, cosT, sinT, Vtf);

        attn_f16_kernel<<<dim3(NH, SEQQ / 64), blk, 0, stream>>>(
            QKVf, QKVf + HIDDEN, Vtf, kpv + HIDDEN, kpv + 2 * HIDDEN, gate, Of);

        cvt_f16_kernel<<<nW8 / 256, blk, 0, stream>>>(Wo, Wof, nW8);
        gemm_f16_kernel<float><<<dim3(HIDDEN / 128, SEQQ / 128), blk, 0, stream>>>(
            Of, Wof, out, HIDDEN, HIDDEN, SEQQ);
    } else {
        // fp32 fallback
        float* ws = (float*)d_ws;
        float* qb   = ws;
        float* kb   = ws + SH;
        float* vb   = ws + 2 * SH;
        float* kpb  = ws + 3 * SH;
        float* vpb  = kpb + (size_t)PLEN * HIDDEN;
        float* cT   = vpb + (size_t)PLEN * HIDDEN;
        float* sT   = cT + (size_t)SEQQ * 64;
        rope_table_kernel<<<SEQQ, 64, 0, stream>>>(pos, cT, sT);
        dim3 gbig(HIDDEN / 128, SEQQ / 128);
        dim3 gsm(HIDDEN / 128, 1);
        gemm_nt_kernel<<<gbig, blk, 0, stream>>>(hidden, Wq, qb, SEQQ, HIDDEN, HIDDEN);
        gemm_nt_kernel<<<gbig, blk, 0, stream>>>(hidden, Wk, kb, SEQQ, HIDDEN, HIDDEN);
        gemm_nt_kernel<<<gbig, blk, 0, stream>>>(hidden, Wv, vb, SEQQ, HIDDEN, HIDDEN);
        gemm_nt_kernel<<<gsm, blk, 0, stream>>>(adapter, Wk, kpb, PLEN, HIDDEN, HIDDEN);
        gemm_nt_kernel<<<gsm, blk, 0, stream>>>(adapter, Wv, vpb, PLEN, HIDDEN, HIDDEN);
        rope_apply_kernel<<<(SEQQ * 2048) / 256, 256, 0, stream>>>(qb, kb, cT, sT);
        attn_kernel<<<dim3(SEQQ / QT, NH), blk, 0, stream>>>(qb, kb, vb, kpb, vpb, gate, qb);
        gemm_nt_kernel<<<gbig, blk, 0, stream>>>(qb, Wo, out, SEQQ, HIDDEN, HIDDEN);
    }
}